// Round 13
// baseline (180.830 us; speedup 1.0000x reference)
//
#include <hip/hip_runtime.h>
#include <math.h>

#define N_ROWS 16384
#define M_COLS 8192
#define TPB 256
#define PAIR_BLOCKS 1024            // 4 waves/block: wave = 1 i-strip(16) x 1 j-quarter(2048)
#define EDGE_BLOCKS 1024
#define EU 8                        // edges per thread (E=2e6, guarded)
#define GRID_BLOCKS (PAIR_BLOCKS + EDGE_BLOCKS)   // 2048
#define JTILES 128                  // 2048 j per wave / 16

typedef _Float16 h8 __attribute__((ext_vector_type(8)));
typedef float f32x4 __attribute__((ext_vector_type(4)));

#define C2 2.0813689810056077f      // log2(e)^2
#define MU 0.125f                   // exact softmax-row mean (D=8)
#define ROWB 32                     // packed edge row: {8xf16 raw z, f32 gamma, pad}

// ---------- kernel 1: row softmax -> MFMA operands + edge pack + scalars ----
// zm[i][0..31] f16: 0..7 = -2*C2*(z_d - MU), 8..31 = 0   (MFMA A, K=32 padded)
// wm[j][0..31] f16: 0..7 = (w_d - MU), 8..31 = 0          (MFMA B)
// szz[i] = C2*||z'||^2, sww[j] = C2*||w'||^2 (f32, outside MFMA -> no cancellation)
// eg/ec = exp(gamma); zpack/wpack = raw f16 row + raw gamma (edge path, verified r11)
__global__ __launch_bounds__(TPB) void rownorm_kernel(
    const float* __restrict__ lz, const float* __restrict__ gr,
    const float* __restrict__ lw, const float* __restrict__ gc,
    _Float16* __restrict__ zm, float* __restrict__ szz, float* __restrict__ eg,
    char* __restrict__ zpack,
    _Float16* __restrict__ wm, float* __restrict__ sww, float* __restrict__ ec,
    char* __restrict__ wpack)
{
    int gi = blockIdx.x * TPB + threadIdx.x;
    const float *src, *g;
    _Float16* dm;
    float *dq, *de;
    char* dp8;
    float ascale;                    // A side gets -2*C2, B side gets 1
    int i;
    if (gi < N_ROWS) { src = lz; g = gr; dm = zm; dq = szz; de = eg; dp8 = zpack; ascale = -2.f * C2; i = gi; }
    else             { src = lw; g = gc; dm = wm; dq = sww; de = ec; dp8 = wpack; ascale = 1.f;        i = gi - N_ROWS; }

    const float4* sp = (const float4*)(src + (size_t)i * 8);
    float4 a = sp[0], b = sp[1];
    float v[8] = {a.x, a.y, a.z, a.w, b.x, b.y, b.z, b.w};
    float m = v[0];
    #pragma unroll
    for (int d = 1; d < 8; d++) m = fmaxf(m, v[d]);
    float s = 0.f;
    #pragma unroll
    for (int d = 0; d < 8; d++) { v[d] = __expf(v[d] - m); s += v[d]; }
    float inv = 1.f / s;
    float sq = 0.f;
    h8 hraw, hm;
    #pragma unroll
    for (int d = 0; d < 8; d++) {
        v[d] *= inv;
        hraw[d] = (_Float16)v[d];            // raw for edge
        float c = v[d] - MU;                 // centered
        sq = fmaf(c, c, sq);
        hm[d] = (_Float16)(ascale * c);      // MFMA operand
    }
    float gam = g[i];
    dq[i] = C2 * sq;
    de[i] = __expf(gam);
    _Float16* mr = dm + (size_t)i * 32;
    h8 zero8 = (h8)(_Float16)0.f;
    *(h8*)mr = hm;                           // k 0..7
    *(h8*)(mr + 8)  = zero8;                 // k 8..15
    *(h8*)(mr + 16) = zero8;                 // k 16..23
    *(h8*)(mr + 24) = zero8;                 // k 24..31
    char* rp = dp8 + (size_t)i * ROWB;
    *(h8*)rp = hraw;
    *(float*)(rp + 16) = gam;
}

// ---------- kernel 2: fused MFMA-pair + edge (role by bid&1) ----------
// pair (even, 1024 blocks x 4 waves): per wave: fixed A-frag (16 i-rows),
//   sweep 128 j-tiles: mfma cross-term -> +szz+sww -> sqrt -> exp2(-) ->
//   weighted acc. Trans pipe is the floor (~14 us); VALU dot eliminated.
// edge (odd, 1024 blocks, EU=8): verified round-11 packed-row gather path.
__global__ __launch_bounds__(TPB) void fused_kernel(
    const _Float16* __restrict__ zm, const float* __restrict__ szz,
    const float* __restrict__ eg,
    const _Float16* __restrict__ wm, const float* __restrict__ sww,
    const float* __restrict__ ec,
    const char* __restrict__ zpack, const char* __restrict__ wpack,
    const float* __restrict__ wt,
    const int* __restrict__ ridx, const int* __restrict__ cidx, int E,
    double* __restrict__ pair_part, double* __restrict__ edge_part)
{
    __shared__ double sred[TPB];
    const int t   = threadIdx.x;
    const int bid = blockIdx.x;

    if ((bid & 1) == 0) {
        // ================= PAIR ROLE (MFMA) =================
        const int lane = t & 63;
        const int wv   = t >> 6;
        const int gw   = (bid >> 1) * 4 + wv;   // 0..4095
        const int strip = gw >> 2;              // 0..1023 -> i0
        const int jq    = gw & 3;               // j-quarter
        const int i0    = strip * 16;
        const int ksl   = lane >> 4;            // 0..3
        const int l15   = lane & 15;

        // A fragment: row = i0 + (lane&15), k-slice = 8*ksl (fixed for sweep)
        const h8 afrag = *(const h8*)(zm + (size_t)(i0 + l15) * 32 + ksl * 8);
        // D rows this lane owns: i0 + 4*ksl + r  (fixed for sweep)
        float szz4[4], eg4[4];
        #pragma unroll
        for (int r = 0; r < 4; r++) {
            szz4[r] = szz[i0 + 4 * ksl + r];
            eg4[r]  = eg [i0 + 4 * ksl + r];
        }

        const f32x4 zero4 = {0.f, 0.f, 0.f, 0.f};
        float acc = 0.f;

        // software-pipelined j-sweep: load t+1 while computing t
        int j0 = jq * 2048;
        int jcol = j0 + l15;
        h8    bf  = *(const h8*)(wm + (size_t)jcol * 32 + ksl * 8);
        float swl = sww[jcol];
        float ecl = ec[jcol];

        for (int jt = 0; jt < JTILES; jt++) {
            h8 bfn; float swn, ecn;
            if (jt < JTILES - 1) {
                int jn = j0 + (jt + 1) * 16 + l15;
                bfn = *(const h8*)(wm + (size_t)jn * 32 + ksl * 8);
                swn = sww[jn];
                ecn = ec[jn];
            }
            f32x4 cr = __builtin_amdgcn_mfma_f32_16x16x32_f16(afrag, bf, zero4, 0, 0, 0);
            float s = 0.f;
            #pragma unroll
            for (int r = 0; r < 4; r++) {
                float vsum = fmaxf(cr[r] + szz4[r] + swl, 0.f);
                float dd, pr;
                asm("v_sqrt_f32 %0, %1" : "=v"(dd) : "v"(vsum));
                asm("v_exp_f32 %0, -%1" : "=v"(pr) : "v"(dd));   // e^{-dist}
                s = fmaf(eg4[r], pr, s);
            }
            acc = fmaf(ecl, s, acc);
            bf = bfn; swl = swn; ecl = ecn;
        }

        sred[t] = (double)acc;
        __syncthreads();
        for (int sh = TPB / 2; sh > 0; sh >>= 1) {
            if (t < sh) sred[t] += sred[t + sh];
            __syncthreads();
        }
        if (t == 0) pair_part[bid >> 1] = sred[0];
    } else {
        // ================= EDGE ROLE (round-11 verified) =================
        const int er  = bid >> 1;                   // 0..1023
        const int tid = er * TPB + t;
        const int e0  = tid * EU;                   // E % 8 == 0
        double local = 0.0;
        if (e0 < E) {
            int4   rr0 = *(const int4*)(ridx + e0);
            int4   rr1 = *(const int4*)(ridx + e0 + 4);
            int4   cc0 = *(const int4*)(cidx + e0);
            int4   cc1 = *(const int4*)(cidx + e0 + 4);
            float4 wtA = *(const float4*)(wt + e0);
            float4 wtB = *(const float4*)(wt + e0 + 4);
            int   r[EU]  = {rr0.x, rr0.y, rr0.z, rr0.w, rr1.x, rr1.y, rr1.z, rr1.w};
            int   c[EU]  = {cc0.x, cc0.y, cc0.z, cc0.w, cc1.x, cc1.y, cc1.z, cc1.w};
            float wv[EU] = {wtA.x, wtA.y, wtA.z, wtA.w, wtB.x, wtB.y, wtB.z, wtB.w};
            h8 zr[EU], wr[EU];
            float grv[EU], gcv[EU];
            #pragma unroll
            for (int u = 0; u < EU; u++) {
                const char* zp = zpack + (size_t)r[u] * ROWB;
                const char* wp = wpack + (size_t)c[u] * ROWB;
                zr[u]  = *(const h8*)zp;
                wr[u]  = *(const h8*)wp;
                grv[u] = *(const float*)(zp + 16);
                gcv[u] = *(const float*)(wp + 16);
            }
            #pragma unroll
            for (int u = 0; u < EU; u++) {
                h8 dv = zr[u] - wr[u];
                float s = 0.f;
                #pragma unroll
                for (int qd = 0; qd < 8; qd++) {
                    float f = (float)dv[qd];
                    s = fmaf(f, f, s);
                }
                float dist;
                asm("v_sqrt_f32 %0, %1" : "=v"(dist) : "v"(s));
                local += (double)(wv[u] * (grv[u] + gcv[u] - dist));
            }
        }
        sred[t] = local;
        __syncthreads();
        for (int s2 = TPB / 2; s2 > 0; s2 >>= 1) {
            if (t < s2) sred[t] += sred[t + s2];
            __syncthreads();
        }
        if (t == 0) edge_part[er] = sred[0];
    }
}

// ---------- kernel 3: final deterministic combine ----------
__global__ __launch_bounds__(TPB) void final_kernel(
    const double* __restrict__ pp, int np,
    const double* __restrict__ ep, int ne,
    float* __restrict__ out)
{
    __shared__ double sred[TPB];
    const int t = threadIdx.x;
    double s1 = 0.0, s2 = 0.0;
    for (int i = t; i < np; i += TPB) s1 += pp[i];
    for (int i = t; i < ne; i += TPB) s2 += ep[i];
    sred[t] = s1;
    __syncthreads();
    for (int s = TPB / 2; s > 0; s >>= 1) {
        if (t < s) sred[t] += sred[t + s];
        __syncthreads();
    }
    double pair_sum = sred[0];
    __syncthreads();
    sred[t] = s2;
    __syncthreads();
    for (int s = TPB / 2; s > 0; s >>= 1) {
        if (t < s) sred[t] += sred[t + s];
        __syncthreads();
    }
    if (t == 0) {
        double edge_sum = sred[0];
        double cf = exp(-1.0e-6);   // exp(-EPS) factored out of the pair term
        out[0] = (float)(cf * pair_sum - edge_sum);
    }
}

extern "C" void kernel_launch(void* const* d_in, const int* in_sizes, int n_in,
                              void* d_out, int out_size, void* d_ws, size_t ws_size,
                              hipStream_t stream)
{
    const float* gamma_rows = (const float*)d_in[0];   // [N]
    const float* gamma_cols = (const float*)d_in[1];   // [M]
    const float* latent_z   = (const float*)d_in[2];   // [N,8]
    const float* latent_w   = (const float*)d_in[3];   // [M,8]
    const float* weights    = (const float*)d_in[4];   // [E]
    const int*   rows_idx   = (const int*)d_in[5];     // [E]
    const int*   col_idx    = (const int*)d_in[6];     // [E]
    float* out = (float*)d_out;
    const int E = in_sizes[4];

    // workspace (segments 256B-aligned); total ~2.5 MB
    char* base = (char*)d_ws;
    size_t off = 0;
    _Float16* zm = (_Float16*)(base + off); off += (size_t)N_ROWS * 32 * 2;  // 1 MB
    _Float16* wm = (_Float16*)(base + off); off += (size_t)M_COLS * 32 * 2;  // 512K
    float* szz = (float*)(base + off); off += (size_t)N_ROWS * 4;            //  64K
    float* eg  = (float*)(base + off); off += (size_t)N_ROWS * 4;            //  64K
    float* sww = (float*)(base + off); off += (size_t)M_COLS * 4;            //  32K
    float* ec  = (float*)(base + off); off += (size_t)M_COLS * 4;            //  32K
    char* zpack = base + off; off += (size_t)N_ROWS * ROWB;                  // 512K
    char* wpack = base + off; off += (size_t)M_COLS * ROWB;                  // 256K
    double* pair_part = (double*)(base + off); off += (size_t)PAIR_BLOCKS * 8;
    double* edge_part = (double*)(base + off); off += (size_t)EDGE_BLOCKS * 8;
    (void)ws_size;

    rownorm_kernel<<<(N_ROWS + M_COLS) / TPB, TPB, 0, stream>>>(
        latent_z, gamma_rows, latent_w, gamma_cols,
        zm, szz, eg, zpack, wm, sww, ec, wpack);
    fused_kernel<<<GRID_BLOCKS, TPB, 0, stream>>>(
        zm, szz, eg, wm, sww, ec, zpack, wpack,
        weights, rows_idx, col_idx, E, pair_part, edge_part);
    final_kernel<<<1, TPB, 0, stream>>>(pair_part, PAIR_BLOCKS,
                                        edge_part, EDGE_BLOCKS, out);
}